// Round 23
// baseline (604.528 us; speedup 1.0000x reference)
//
#include <hip/hip_runtime.h>

#define N_ 50000
#define E_ 800000
#define G_ 1024

// ---------- helpers ----------
__device__ __forceinline__ float lrelu(float v){ return v > 0.f ? v : 0.01f*v; }
__device__ __forceinline__ float wsum64(float t){
  #pragma unroll
  for (int off = 32; off > 0; off >>= 1) t += __shfl_xor(t, off);
  return t;
}
__device__ __forceinline__ float f4get(const float4& v, int kk){
  return kk==0 ? v.x : kk==1 ? v.y : kk==2 ? v.z : v.w;   // kk static under unroll
}

// transposed-weight layout offsets (floats)
#define OFF_LIN1T 0
#define OFF_W1AT  4096
#define OFF_W2T   8192
#define OFF_ATOMT 12288
#define OFF_MOLT  16384
#define OFF_G0IH  20480
#define OFF_G0HH  32768
#define OFF_G1IH  45056
#define OFF_G1HH  57344
#define OFF_MGIH  69632
#define OFF_MGHH  81920
#define OFF_WV    94208
#define OFF_W1E   94272
#define TW_TOTAL  98368

// ---------- weight prep ----------
__global__ void k_prep(const float* lin1W, const float* gW1, const float* gW2,
                       const float* atomW, const float* molW, const float* molAttDst,
                       const float* g0ih, const float* g0hh,
                       const float* g1ih, const float* g1hh,
                       const float* mgih, const float* mghh, float* tw) {
  int t = blockIdx.x*256 + threadIdx.x;
  if (t < 20480) {                       // five [64 x cin] mats -> [64][64] transposed
    int seg = t >> 12;
    int i = t & 4095; int k = i >> 6, c = i & 63;
    const float* src = seg==0?lin1W: seg==1?gW1: seg==2?gW2: seg==3?atomW: molW;
    int stride = (seg==1)?80:64;
    tw[t] = src[c*stride + k];
  } else if (t < 94208) {                // six [192x64] GRU mats -> [64][192]
    int i = t - 20480; int seg = i / 12288; int j = i % 12288;
    int k = j / 192, r = j % 192;
    const float* src = seg==0?g0ih: seg==1?g0hh: seg==2?g1ih: seg==3?g1hh: seg==4?mgih: mghh;
    tw[t] = src[r*64 + k];
  } else if (t < 94272) {                // wv[k] = sum_j att_dst[j] * molW[j][k]
    int k = t - 94208;
    float acc = 0.f;
    for (int j = 0; j < 64; j++) acc += molAttDst[j]*molW[j*64+k];
    tw[t] = acc;
  } else if (t < TW_TOTAL) {
    // W1E[(i*16 + j)*4 + f] = gW1[(j*4+c)*80 + 64 + d4*4 + f], i = c*4+d4
    int i2 = t - OFF_W1E;
    int f = i2 & 3, j = (i2 >> 2) & 15, i = i2 >> 6;
    int c = i >> 2, d4 = i & 3;
    tw[t] = gW1[(j*4+c)*80 + 64 + d4*4 + f];
  }
}

// ---------- sort by dst: histogram ----------
__global__ void k_hist(const int* __restrict__ ei, int* __restrict__ cnt) {
  int t = blockIdx.x*blockDim.x + threadIdx.x;
  if (t >= E_) return;
  atomicAdd(cnt + ei[E_ + t], 1);
}

// ---------- exclusive scan over N (one block, 1024 threads) ----------
__global__ void k_scan(const int* __restrict__ cnt, int* __restrict__ off) {
  __shared__ int part[1024];
  const int PER = (N_ + 1023) / 1024;
  int t = threadIdx.x;
  int b0 = t * PER;
  int s = 0;
  for (int i = 0; i < PER; i++) { int idx = b0 + i; if (idx < N_) s += cnt[idx]; }
  part[t] = s; __syncthreads();
  for (int d = 1; d < 1024; d <<= 1) {
    int v = (t >= d) ? part[t-d] : 0;
    __syncthreads();
    part[t] += v;
    __syncthreads();
  }
  int run = (t == 0) ? 0 : part[t-1];
  for (int i = 0; i < PER; i++) {
    int idx = b0 + i;
    if (idx <= N_) { off[idx] = run; if (idx < N_) run += cnt[idx]; }
  }
}

// ---------- rank: build sorted src/dst/eid lists ----------
__global__ void k_rank(const int* __restrict__ ei, const int* __restrict__ off,
                       int* __restrict__ rnk, int* __restrict__ srcS,
                       int* __restrict__ dstS, int* __restrict__ eidS) {
  int t = blockIdx.x*blockDim.x + threadIdx.x;
  if (t >= E_) return;
  int d = ei[E_ + t];
  int r = atomicAdd(rnk + d, 1);
  int p = off[d] + r;
  srcS[p] = ei[t];
  dstS[p] = d;
  eidS[p] = t;
}

// ---------- graph offsets from sorted batch ----------
__global__ void k_goff(const int* __restrict__ batch, int* __restrict__ goff) {
  int t = blockIdx.x*blockDim.x + threadIdx.x;
  if (t >= N_) return;
  int b = batch[t];
  if (t == 0) { for (int g = 0; g <= b; g++) goff[g] = 0; }
  else { int pb = batch[t-1]; for (int g = pb+1; g <= b; g++) goff[g] = t; }
  if (t == N_-1) { for (int g = b+1; g <= G_; g++) goff[g] = N_; }
}

// ---------- fused lin1 + gate node precompute: 8 nodes/wave, LDS-broadcast ----------
__global__ void k_node8(const float* __restrict__ x, const float* __restrict__ lin1T,
                        const float* __restrict__ lin1b,
                        const float* __restrict__ w1aT, const float* __restrict__ w2T,
                        const float* __restrict__ attr,
                        float* __restrict__ x1o, float* __restrict__ g1,
                        float* __restrict__ g2, float* __restrict__ gr) {
  __shared__ float ts[4][8][64];
  int w = threadIdx.x >> 6, lane = threadIdx.x & 63;
  int base = (blockIdx.x*4 + w)*8;
  if (base >= N_) return;
  #pragma unroll
  for (int r = 0; r < 8; r++) {
    int row = min(base + r, N_-1);
    ts[w][r][lane] = x[(size_t)row*64 + lane];
  }
  float a[8];
  #pragma unroll
  for (int r = 0; r < 8; r++) a[r] = lin1b[lane];
  #pragma unroll 1
  for (int k4 = 0; k4 < 64; k4 += 4) {
    float4 x4[8];
    #pragma unroll
    for (int r = 0; r < 8; r++) x4[r] = *(const float4*)&ts[w][r][k4];
    #pragma unroll
    for (int kk = 0; kk < 4; kk++) {
      float wv = lin1T[(k4+kk)*64 + lane];
      #pragma unroll
      for (int r = 0; r < 8; r++) a[r] += f4get(x4[r], kk) * wv;
    }
  }
  #pragma unroll
  for (int r = 0; r < 8; r++) {
    a[r] = lrelu(a[r]);
    if (base + r < N_) x1o[(size_t)(base+r)*64 + lane] = a[r];
    ts[w][r][lane] = a[r];                 // restage x1 (same wave)
  }
  float b1[8], b2[8];
  #pragma unroll
  for (int r = 0; r < 8; r++) { b1[r] = 0.f; b2[r] = 0.f; }
  #pragma unroll 1
  for (int k4 = 0; k4 < 64; k4 += 4) {
    float4 a4[8];
    #pragma unroll
    for (int r = 0; r < 8; r++) a4[r] = *(const float4*)&ts[w][r][k4];
    #pragma unroll
    for (int kk = 0; kk < 4; kk++) {
      float w1 = w1aT[(k4+kk)*64 + lane];
      float w2v = w2T[(k4+kk)*64 + lane];
      #pragma unroll
      for (int r = 0; r < 8; r++) {
        float xk = f4get(a4[r], kk);
        b1[r] += xk * w1;
        b2[r] += xk * w2v;
      }
    }
  }
  #pragma unroll
  for (int r = 0; r < 8; r++) {
    if (base + r < N_) {
      g1[(size_t)(base+r)*64 + lane] = b1[r];
      g2[(size_t)(base+r)*64 + lane] = b2[r];
    }
  }
  float at = attr[lane];
  #pragma unroll
  for (int r = 0; r < 8; r++) {
    float t = wsum64(a[r] * at);
    if (lane == 0 && base + r < N_) gr[base+r] = t;
  }
}

// ---------- GATE edge logits over SORTED edges: coalesced ae write, no ipos ----------
__global__ void k_edge1(const int* __restrict__ srcS, const int* __restrict__ dstS,
                        const int* __restrict__ eidS, const float* __restrict__ eattr,
                        const float* __restrict__ g1, const float* __restrict__ gr,
                        const float* __restrict__ W1E, const float* __restrict__ attl,
                        float* __restrict__ ae) {
  int wid = (blockIdx.x*blockDim.x + threadIdx.x) >> 6;
  int lane = threadIdx.x & 63;
  int g = lane >> 4, j = lane & 15;
  if (wid >= E_/16) return;
  int p0 = wid*16;
  float wr[64];
  #pragma unroll
  for (int i = 0; i < 16; i++) {
    float4 v = ((const float4*)W1E)[i*16 + j];
    wr[i*4+0] = v.x; wr[i*4+1] = v.y; wr[i*4+2] = v.z; wr[i*4+3] = v.w;
  }
  float4 al = ((const float4*)attl)[j];
  float ea[4]; int srce[4]; float grv[4];
  #pragma unroll
  for (int it = 0; it < 4; it++) {
    int p = p0 + it*4 + g;
    int eid = eidS[p];
    ea[it] = eattr[(size_t)eid*16 + j];    // 64B gather per 16-lane group
    srce[it] = srcS[p];
    grv[it] = gr[dstS[p]];                 // cache-sequential (sorted by dst)
  }
  // software-pipelined g1 row gathers (2-deep)
  float4 gv = *(const float4*)(g1 + (size_t)srce[0]*64 + j*4);
  #pragma unroll
  for (int it = 0; it < 4; it++) {
    float4 gnext;
    if (it < 3) gnext = *(const float4*)(g1 + (size_t)srce[it+1]*64 + j*4);
    float a0 = gv.x, a1 = gv.y, a2 = gv.z, a3 = gv.w;
    #pragma unroll
    for (int d = 0; d < 16; d++) {
      float ead = __shfl(ea[it], g*16 + d);
      a0 += ead * wr[0*16 + d];
      a1 += ead * wr[1*16 + d];
      a2 += ead * wr[2*16 + d];
      a3 += ead * wr[3*16 + d];
    }
    float t = lrelu(a0)*al.x + lrelu(a1)*al.y + lrelu(a2)*al.z + lrelu(a3)*al.w;
    t += __shfl_xor(t, 1); t += __shfl_xor(t, 2);
    t += __shfl_xor(t, 4); t += __shfl_xor(t, 8);
    if (j == 0) ae[p0 + it*4 + g] = lrelu(t + grv[it]);   // coalesced write
    gv = gnext;
  }
}

// ---------- segmented softmax-attention reduce (wave per segment, no atomics/LDS) ----------
template<int MODE>
__global__ void k_seg(const float* __restrict__ aval, const float* __restrict__ asrc,
                      const float* __restrict__ adst, const int* __restrict__ srcS,
                      const int* __restrict__ off, const float* __restrict__ X,
                      float* __restrict__ out, int nseg) {
  int wid = (blockIdx.x*blockDim.x + threadIdx.x) >> 6;
  int lane = threadIdx.x & 63;
  if (wid >= nseg) return;
  int s0 = off[wid], s1 = off[wid+1];
  float adc = MODE ? adst[wid] : 0.f;
  float m = -1e30f, s = 0.f, acc = 0.f;
  for (int b = s0; b < s1; b += 64) {
    int p = b + lane;
    bool ok = p < s1;
    int sr = 0; float v = -1e30f;
    if (ok) {
      sr = srcS ? srcS[p] : p;
      if (MODE) v = lrelu(asrc[sr] + adc);
      else      v = aval[p];
    }
    float cm = v;
    #pragma unroll
    for (int o = 32; o > 0; o >>= 1) cm = fmaxf(cm, __shfl_xor(cm, o));
    float mnew = fmaxf(m, cm);
    float scale = __expf(m - mnew);
    s *= scale; acc *= scale; m = mnew;
    float ev = ok ? __expf(v - m) : 0.f;
    s += wsum64(ev);
    int cnt = min(64, s1 - b);
    int q = 0;
    for (; q + 4 <= cnt; q += 4) {
      int   i0 = __shfl(sr, q),   i1 = __shfl(sr, q+1),
            i2 = __shfl(sr, q+2), i3 = __shfl(sr, q+3);
      float w0 = __shfl(ev, q),   w1 = __shfl(ev, q+1),
            w2 = __shfl(ev, q+2), w3 = __shfl(ev, q+3);
      float v0 = X[(size_t)i0*64 + lane];
      float v1 = X[(size_t)i1*64 + lane];
      float v2 = X[(size_t)i2*64 + lane];
      float v3 = X[(size_t)i3*64 + lane];
      acc += w0*v0; acc += w1*v1; acc += w2*v2; acc += w3*v3;
    }
    for (; q < cnt; q++) {
      int i0 = __shfl(sr, q);
      float w0 = __shfl(ev, q);
      acc += w0 * X[(size_t)i0*64 + lane];
    }
  }
  out[(size_t)wid*64 + lane] = acc / (s + 1e-16f);
}

// ---------- mol-readout segmented softmax: block (4 waves) per graph, LDS merge ----------
__global__ void k_segg(const float* __restrict__ asrc, const float* __restrict__ adst,
                       const int* __restrict__ goff, const float* __restrict__ X,
                       float* __restrict__ out) {
  __shared__ float mS[4], sS[4], accS[4][64];
  int gph = blockIdx.x;
  int lane = threadIdx.x & 63, w = threadIdx.x >> 6;
  int s0 = goff[gph], s1 = goff[gph+1];
  float adc = adst[gph];
  int len = s1 - s0;
  int qlen = (len + 3) >> 2;
  int a0 = s0 + w*qlen, a1 = min(s1, a0 + qlen);
  float m = -1e30f, s = 0.f, acc = 0.f;
  for (int b = a0; b < a1; b += 64) {
    int p = b + lane;
    bool ok = p < a1;
    float v = ok ? lrelu(asrc[p] + adc) : -1e30f;
    float cm = v;
    #pragma unroll
    for (int o = 32; o > 0; o >>= 1) cm = fmaxf(cm, __shfl_xor(cm, o));
    float mnew = fmaxf(m, cm);
    float scale = __expf(m - mnew);
    s *= scale; acc *= scale; m = mnew;
    float ev = ok ? __expf(v - m) : 0.f;
    s += wsum64(ev);
    int cnt = min(64, a1 - b);
    int q = 0;
    for (; q + 4 <= cnt; q += 4) {
      float w0 = __shfl(ev, q),   w1 = __shfl(ev, q+1),
            w2 = __shfl(ev, q+2), w3 = __shfl(ev, q+3);
      float v0 = X[(size_t)(b+q  )*64 + lane];
      float v1 = X[(size_t)(b+q+1)*64 + lane];
      float v2 = X[(size_t)(b+q+2)*64 + lane];
      float v3 = X[(size_t)(b+q+3)*64 + lane];
      acc += w0*v0; acc += w1*v1; acc += w2*v2; acc += w3*v3;
    }
    for (; q < cnt; q++) acc += __shfl(ev, q) * X[(size_t)(b+q)*64 + lane];
  }
  if (lane == 0) { mS[w] = m; sS[w] = s; }
  accS[w][lane] = acc;
  __syncthreads();
  if (w == 0) {
    float m0 = fmaxf(fmaxf(mS[0], mS[1]), fmaxf(mS[2], mS[3]));
    float e0 = __expf(mS[0]-m0), e1 = __expf(mS[1]-m0),
          e2 = __expf(mS[2]-m0), e3 = __expf(mS[3]-m0);
    float st = sS[0]*e0 + sS[1]*e1 + sS[2]*e2 + sS[3]*e3;
    float at = accS[0][lane]*e0 + accS[1][lane]*e1 + accS[2][lane]*e2 + accS[3][lane]*e3;
    out[(size_t)gph*64 + lane] = at / (st + 1e-16f);
  }
}

// ---------- GRU (8 nodes/wave, LDS-broadcast, single pass, merged r/z accumulators) ----------
template<bool MV>
__global__ void k_gru8(const float* __restrict__ hpre, const float* __restrict__ bpre,
                       const float* __restrict__ hx,
                       const float* __restrict__ WihT, const float* __restrict__ WhhT,
                       const float* __restrict__ bih, const float* __restrict__ bhh,
                       float* __restrict__ outg, int n,
                       const float* __restrict__ WT, const float* __restrict__ v1,
                       const float* __restrict__ v2,
                       float* __restrict__ y, float* __restrict__ d1,
                       float* __restrict__ d2) {
  __shared__ float hs[4][8][64], xs[4][8][64];     // 16 KB
  int w = threadIdx.x >> 6, lane = threadIdx.x & 63;
  int base = (blockIdx.x*4 + w)*8;
  if (base >= n) return;
  #pragma unroll
  for (int r = 0; r < 8; r++) {
    int row = min(base + r, n-1);
    float hv = hpre[(size_t)row*64 + lane] + bpre[lane];
    hv = hv > 0.f ? hv : expm1f(hv);               // elu
    hs[w][r][lane] = hv;
    xs[w][r][lane] = hx[(size_t)row*64 + lane];
  }
  float a0[8], a1[8], ni[8], nh[8];
  #pragma unroll
  for (int r = 0; r < 8; r++) {
    a0[r] = bih[lane]    + bhh[lane];
    a1[r] = bih[64+lane] + bhh[64+lane];
    ni[r] = bih[128+lane];
    nh[r] = bhh[128+lane];
  }
  #pragma unroll 1
  for (int k2 = 0; k2 < 64; k2 += 2) {
    float2 h2[8], x2[8];
    #pragma unroll
    for (int r = 0; r < 8; r++) {
      h2[r] = *(const float2*)&hs[w][r][k2];       // uniform addr -> broadcast
      x2[r] = *(const float2*)&xs[w][r][k2];
    }
    #pragma unroll
    for (int kk = 0; kk < 2; kk++) {
      int k = k2 + kk;
      const float* wi = WihT + k*192;
      const float* wh = WhhT + k*192;
      float wi0 = wi[lane], wi1 = wi[64+lane], wi2 = wi[128+lane];
      float wh0 = wh[lane], wh1 = wh[64+lane], wh2 = wh[128+lane];
      #pragma unroll
      for (int r = 0; r < 8; r++) {
        float hk = kk ? h2[r].y : h2[r].x;
        float xk = kk ? x2[r].y : x2[r].x;
        a0[r] += hk*wi0; a0[r] += xk*wh0;
        a1[r] += hk*wi1; a1[r] += xk*wh1;
        ni[r] += hk*wi2; nh[r] += xk*wh2;
      }
    }
  }
  float o[8];
  #pragma unroll
  for (int r = 0; r < 8; r++) {
    float rr = 1.f/(1.f+__expf(-a0[r]));
    float zz = 1.f/(1.f+__expf(-a1[r]));
    float nn = tanhf(ni[r] + rr*nh[r]);
    float xv = xs[w][r][lane];
    float ov = (1.f - zz)*nn + zz*xv;
    o[r] = ov > 0.f ? ov : 0.f;                    // relu
    if (base + r < n) outg[(size_t)(base+r)*64 + lane] = o[r];
  }
  if (MV) {
    #pragma unroll
    for (int r = 0; r < 8; r++) hs[w][r][lane] = o[r];   // restage (same wave)
    float ay[8];
    #pragma unroll
    for (int r = 0; r < 8; r++) ay[r] = 0.f;
    #pragma unroll 1
    for (int k4 = 0; k4 < 64; k4 += 4) {
      float4 o4[8];
      #pragma unroll
      for (int r = 0; r < 8; r++) o4[r] = *(const float4*)&hs[w][r][k4];
      #pragma unroll
      for (int kk = 0; kk < 4; kk++) {
        float wv = WT[(k4+kk)*64 + lane];
        #pragma unroll
        for (int r = 0; r < 8; r++) ay[r] += f4get(o4[r], kk) * wv;
      }
    }
    #pragma unroll
    for (int r = 0; r < 8; r++)
      if (base + r < n) y[(size_t)(base+r)*64 + lane] = ay[r];
    float va = v1[lane];
    #pragma unroll
    for (int r = 0; r < 8; r++) {
      float t = wsum64(ay[r] * va);
      if (lane == 0 && base + r < n) d1[base+r] = t;
    }
    if (v2) {
      float vb = v2[lane];
      #pragma unroll
      for (int r = 0; r < 8; r++) {
        float t = wsum64(ay[r] * vb);
        if (lane == 0 && base + r < n) d2[base+r] = t;
      }
    }
  }
}

// ---------- small GRU for mol readout (4 rows/wave, unroll 2) ----------
__global__ void k_gru_sm(const float* __restrict__ hpre, const float* __restrict__ bpre,
                         const float* __restrict__ hx,
                         const float* __restrict__ WihT, const float* __restrict__ WhhT,
                         const float* __restrict__ bih, const float* __restrict__ bhh,
                         float* __restrict__ outg, int n) {
  int wid = (blockIdx.x*blockDim.x + threadIdx.x) >> 6;
  int lane = threadIdx.x & 63;
  int base = wid*4;
  if (base >= n) return;
  float h[4], xv[4];
  #pragma unroll
  for (int r = 0; r < 4; r++) {
    float hv = hpre[(size_t)(base+r)*64 + lane] + bpre[lane];
    h[r] = hv > 0.f ? hv : expm1f(hv);
    xv[r] = hx[(size_t)(base+r)*64 + lane];
  }
  float ai[4][3], ah[4][3];
  #pragma unroll
  for (int r = 0; r < 4; r++)
    #pragma unroll
    for (int g = 0; g < 3; g++) {
      ai[r][g] = bih[g*64 + lane];
      ah[r][g] = bhh[g*64 + lane];
    }
  #pragma unroll 2
  for (int k = 0; k < 64; k++) {
    const float* wi = WihT + k*192;
    const float* wh = WhhT + k*192;
    float wi0 = wi[lane], wi1 = wi[64+lane], wi2 = wi[128+lane];
    float wh0 = wh[lane], wh1 = wh[64+lane], wh2 = wh[128+lane];
    #pragma unroll
    for (int r = 0; r < 4; r++) {
      float hk = __shfl(h[r], k);
      float xk = __shfl(xv[r], k);
      ai[r][0] += hk*wi0; ai[r][1] += hk*wi1; ai[r][2] += hk*wi2;
      ah[r][0] += xk*wh0; ah[r][1] += xk*wh1; ah[r][2] += xk*wh2;
    }
  }
  #pragma unroll
  for (int r = 0; r < 4; r++) {
    float rr = 1.f/(1.f+__expf(-(ai[r][0]+ah[r][0])));
    float zz = 1.f/(1.f+__expf(-(ai[r][1]+ah[r][1])));
    float nn = tanhf(ai[r][2] + rr*ah[r][2]);
    float ov = (1.f - zz)*nn + zz*xv[r];
    outg[(size_t)(base+r)*64 + lane] = ov > 0.f ? ov : 0.f;
  }
}

// ---------- global_add_pool + relu: block (4 waves) per graph ----------
__global__ void k_pool4(const float* __restrict__ x3, const int* __restrict__ goff,
                        float* __restrict__ pool) {
  __shared__ float red[4][64];
  int gph = blockIdx.x;
  int lane = threadIdx.x & 63, w = threadIdx.x >> 6;
  int s0 = goff[gph], s1 = goff[gph+1];
  float acc = 0.f;
  for (int n = s0 + w; n < s1; n += 4) acc += x3[(size_t)n*64 + lane];
  red[w][lane] = acc;
  __syncthreads();
  if (w == 0) {
    float t = red[0][lane] + red[1][lane] + red[2][lane] + red[3][lane];
    pool[(size_t)gph*64 + lane] = fmaxf(t, 0.f);
  }
}

// ---------- per-graph dot with wv ----------
__global__ void k_dotg(const float* __restrict__ pool, const float* __restrict__ wv,
                       float* __restrict__ adg) {
  int wid = (blockIdx.x*blockDim.x + threadIdx.x) >> 6;
  int lane = threadIdx.x & 63;
  if (wid >= G_) return;
  float t = wsum64(pool[wid*64+lane] * wv[lane]);
  if (lane == 0) adg[wid] = t;
}

// ---------- final projection ----------
__global__ void k_final(const float* __restrict__ pool, const float* __restrict__ w2,
                        const float* __restrict__ b2, float* __restrict__ out) {
  int wid = (blockIdx.x*blockDim.x + threadIdx.x) >> 6;
  int lane = threadIdx.x & 63;
  if (wid >= G_) return;
  float t = wsum64(pool[wid*64+lane] * w2[lane]);
  if (lane == 0) out[wid] = t + b2[0];
}

// ---------- launcher ----------
extern "C" void kernel_launch(void* const* d_in, const int* in_sizes, int n_in,
                              void* d_out, int out_size, void* d_ws, size_t ws_size,
                              hipStream_t stream) {
  const float* x     = (const float*)d_in[0];
  const int*   ei    = (const int*)d_in[1];
  const float* eattr = (const float*)d_in[2];
  const int*   batch = (const int*)d_in[3];
  const float* lin1W = (const float*)d_in[4];
  const float* lin1b = (const float*)d_in[5];
  const float* gattl = (const float*)d_in[6];
  const float* gattr = (const float*)d_in[7];
  const float* gW1   = (const float*)d_in[8];
  const float* gW2   = (const float*)d_in[9];
  const float* gb    = (const float*)d_in[10];
  const float* g0ih  = (const float*)d_in[11];
  const float* g0hh  = (const float*)d_in[12];
  const float* g0bih = (const float*)d_in[13];
  const float* g0bhh = (const float*)d_in[14];
  const float* g1ih  = (const float*)d_in[15];
  const float* g1hh  = (const float*)d_in[16];
  const float* g1bih = (const float*)d_in[17];
  const float* g1bhh = (const float*)d_in[18];
  const float* mgih  = (const float*)d_in[19];
  const float* mghh  = (const float*)d_in[20];
  const float* mgbih = (const float*)d_in[21];
  const float* mgbhh = (const float*)d_in[22];
  const float* atomW = (const float*)d_in[23];
  const float* atomAs= (const float*)d_in[24];
  const float* atomAd= (const float*)d_in[25];
  const float* atomB = (const float*)d_in[26];
  const float* molW  = (const float*)d_in[27];
  const float* molAs = (const float*)d_in[28];
  const float* molAd = (const float*)d_in[29];
  const float* molB  = (const float*)d_in[30];
  const float* lin2W = (const float*)d_in[31];
  const float* lin2b = (const float*)d_in[32];
  float* out = (float*)d_out;
  float* w = (float*)d_ws;

  // ws allocation (floats, 64-aligned)
  size_t o = 0;
  auto alloc = [&](size_t nf){ size_t r = o; o += (nf + 63) & ~(size_t)63; return r; };
  float* tw   = w + alloc(TW_TOTAL);
  float* bufA = w + alloc((size_t)N_*64);   // x1 -> (seg atom out) -> x3
  float* bufB = w + alloc((size_t)N_*64);   // g1 -> (seg gate out) -> x2
  float* bufC = w + alloc((size_t)N_*64);   // g2 -> xs_atom -> xs_mol
  float* ae   = w + alloc(E_);              // sorted GATE logits
  int* srcS   = (int*)(w + alloc(E_));      // src sorted by dst
  int* dstS   = (int*)(w + alloc(E_));      // dst sorted (segment id per pos)
  int* eidS   = (int*)(w + alloc(E_));      // orig edge id per sorted pos
  int* cnt    = (int*)(w + alloc(2*N_));    // cnt[N] + rnk[N] (contiguous for memset)
  int* rnk    = cnt + N_;
  int* off    = (int*)(w + alloc(N_+1));
  float* gr   = w + alloc(N_);
  float* as_  = w + alloc(N_);
  float* ad_  = w + alloc(N_);
  int* goff   = (int*)(w + alloc(G_+1));
  float* pool = w + alloc((size_t)G_*64);
  float* hg   = w + alloc((size_t)G_*64);
  float* adg  = w + alloc(G_);
  (void)rnk;

  const int TB = 256;
  const int NB_nw  = (N_+3)/4;       // wave-per-node blocks (12500)
  const int NB_n32 = (N_+31)/32;     // 4-waves x 8-nodes blocks (1563)
  const int NB_g16 = G_/16;          // 64
  const int NB_e   = (E_+TB-1)/TB;   // thread-per-edge (3125)
  const int NB_n   = (N_+TB-1)/TB;   // thread-per-node (196)
  const int NB_e16 = E_/16/4;        // 16-edges-per-wave blocks (12500)
  const int NB_gw  = G_/4;           // wave-per-graph (256)

  hipMemsetAsync(cnt, 0, (size_t)2*N_*sizeof(int), stream);
  k_prep<<<(TW_TOTAL+TB-1)/TB, TB, 0, stream>>>(lin1W, gW1, gW2, atomW, molW, molAd,
      g0ih, g0hh, g1ih, g1hh, mgih, mghh, tw);
  // counting sort of edges by dst
  k_hist<<<NB_e, TB, 0, stream>>>(ei, cnt);
  k_scan<<<1, 1024, 0, stream>>>(cnt, off);
  k_rank<<<NB_e, TB, 0, stream>>>(ei, off, rnk, srcS, dstS, eidS);
  k_goff<<<NB_n, TB, 0, stream>>>(batch, goff);

  // fused lin1 + GATE node precompute (8 nodes/wave)
  k_node8<<<NB_n32, TB, 0, stream>>>(x, tw+OFF_LIN1T, lin1b, tw+OFF_W1AT, tw+OFF_W2T,
                                     gattr, bufA, bufB, bufC, gr);
  // GATEConv edge pass over sorted edges + segmented softmax reduce
  k_edge1<<<NB_e16, TB, 0, stream>>>(srcS, dstS, eidS, eattr, bufB, gr,
                                     tw+OFF_W1E, gattl, ae);
  k_seg<0><<<NB_nw, TB, 0, stream>>>(ae, nullptr, nullptr, srcS, off, bufC, bufB, N_);
  // gru0 (8 nodes/wave) fused with atom-GAT matvec + dots: x2 in bufB, xs_atom in bufC
  k_gru8<true><<<NB_n32, TB, 0, stream>>>(bufB, gb, bufA, tw+OFF_G0IH, tw+OFF_G0HH,
      g0bih, g0bhh, bufB, N_, tw+OFF_ATOMT, atomAs, atomAd, bufC, as_, ad_);
  // atom GAT reduce
  k_seg<1><<<NB_nw, TB, 0, stream>>>(nullptr, as_, ad_, srcS, off, bufC, bufA, N_);
  // gru1 fused with mol matvec + as dot: x3 in bufA, xs_mol in bufC
  k_gru8<true><<<NB_n32, TB, 0, stream>>>(bufA, atomB, bufB, tw+OFF_G1IH, tw+OFF_G1HH,
      g1bih, g1bhh, bufA, N_, tw+OFF_MOLT, molAs, nullptr, bufC, as_, nullptr);
  // readout: block-per-graph pool
  k_pool4<<<G_, TB, 0, stream>>>(bufA, goff, pool);
  for (int t = 0; t < 2; t++) {
    k_dotg<<<NB_gw, TB, 0, stream>>>(pool, tw+OFF_WV, adg);
    k_segg<<<G_, TB, 0, stream>>>(as_, adg, goff, bufC, hg);
    k_gru_sm<<<NB_g16, TB, 0, stream>>>(hg, molB, pool, tw+OFF_MGIH, tw+OFF_MGHH,
        mgbih, mgbhh, pool, G_);
  }
  k_final<<<NB_gw, TB, 0, stream>>>(pool, lin2W, lin2b, out);
}

// Round 26
// 564.780 us; speedup vs baseline: 1.0704x; 1.0704x over previous
//
#include <hip/hip_runtime.h>

#define N_ 50000
#define E_ 800000
#define G_ 1024

// ---------- helpers ----------
__device__ __forceinline__ float lrelu(float v){ return v > 0.f ? v : 0.01f*v; }
__device__ __forceinline__ float wsum64(float t){
  #pragma unroll
  for (int off = 32; off > 0; off >>= 1) t += __shfl_xor(t, off);
  return t;
}
__device__ __forceinline__ float f4get(const float4& v, int kk){
  return kk==0 ? v.x : kk==1 ? v.y : kk==2 ? v.z : v.w;   // kk static under unroll
}

// transposed-weight layout offsets (floats)
#define OFF_LIN1T 0
#define OFF_W1AT  4096
#define OFF_W2T   8192
#define OFF_ATOMT 12288
#define OFF_MOLT  16384
#define OFF_G0IH  20480
#define OFF_G0HH  32768
#define OFF_G1IH  45056
#define OFF_G1HH  57344
#define OFF_MGIH  69632
#define OFF_MGHH  81920
#define OFF_WV    94208
#define OFF_W1E   94272
#define TW_TOTAL  98368

// ---------- weight prep ----------
__global__ void k_prep(const float* lin1W, const float* gW1, const float* gW2,
                       const float* atomW, const float* molW, const float* molAttDst,
                       const float* g0ih, const float* g0hh,
                       const float* g1ih, const float* g1hh,
                       const float* mgih, const float* mghh, float* tw) {
  int t = blockIdx.x*256 + threadIdx.x;
  if (t < 20480) {                       // five [64 x cin] mats -> [64][64] transposed
    int seg = t >> 12;
    int i = t & 4095; int k = i >> 6, c = i & 63;
    const float* src = seg==0?lin1W: seg==1?gW1: seg==2?gW2: seg==3?atomW: molW;
    int stride = (seg==1)?80:64;
    tw[t] = src[c*stride + k];
  } else if (t < 94208) {                // six [192x64] GRU mats -> [64][192]
    int i = t - 20480; int seg = i / 12288; int j = i % 12288;
    int k = j / 192, r = j % 192;
    const float* src = seg==0?g0ih: seg==1?g0hh: seg==2?g1ih: seg==3?g1hh: seg==4?mgih: mghh;
    tw[t] = src[r*64 + k];
  } else if (t < 94272) {                // wv[k] = sum_j att_dst[j] * molW[j][k]
    int k = t - 94208;
    float acc = 0.f;
    for (int j = 0; j < 64; j++) acc += molAttDst[j]*molW[j*64+k];
    tw[t] = acc;
  } else if (t < TW_TOTAL) {
    // W1E[(i*16 + j)*4 + f] = gW1[(j*4+c)*80 + 64 + d4*4 + f], i = c*4+d4
    int i2 = t - OFF_W1E;
    int f = i2 & 3, j = (i2 >> 2) & 15, i = i2 >> 6;
    int c = i >> 2, d4 = i & 3;
    tw[t] = gW1[(j*4+c)*80 + 64 + d4*4 + f];
  }
}

// ---------- sort by dst: histogram ----------
__global__ void k_hist(const int* __restrict__ ei, int* __restrict__ cnt) {
  int t = blockIdx.x*blockDim.x + threadIdx.x;
  if (t >= E_) return;
  atomicAdd(cnt + ei[E_ + t], 1);
}

// ---------- exclusive scan over N (one block, 1024 threads) ----------
__global__ void k_scan(const int* __restrict__ cnt, int* __restrict__ off) {
  __shared__ int part[1024];
  const int PER = (N_ + 1023) / 1024;
  int t = threadIdx.x;
  int b0 = t * PER;
  int s = 0;
  for (int i = 0; i < PER; i++) { int idx = b0 + i; if (idx < N_) s += cnt[idx]; }
  part[t] = s; __syncthreads();
  for (int d = 1; d < 1024; d <<= 1) {
    int v = (t >= d) ? part[t-d] : 0;
    __syncthreads();
    part[t] += v;
    __syncthreads();
  }
  int run = (t == 0) ? 0 : part[t-1];
  for (int i = 0; i < PER; i++) {
    int idx = b0 + i;
    if (idx <= N_) { off[idx] = run; if (idx < N_) run += cnt[idx]; }
  }
}

// ---------- rank: build sorted src list + inverse position ----------
__global__ void k_rank(const int* __restrict__ ei, const int* __restrict__ off,
                       int* __restrict__ rnk, int* __restrict__ srcS,
                       int* __restrict__ ipos) {
  int t = blockIdx.x*blockDim.x + threadIdx.x;
  if (t >= E_) return;
  int d = ei[E_ + t];
  int r = atomicAdd(rnk + d, 1);
  int p = off[d] + r;
  srcS[p] = ei[t];
  ipos[t] = p;
}

// ---------- graph offsets from sorted batch ----------
__global__ void k_goff(const int* __restrict__ batch, int* __restrict__ goff) {
  int t = blockIdx.x*blockDim.x + threadIdx.x;
  if (t >= N_) return;
  int b = batch[t];
  if (t == 0) { for (int g = 0; g <= b; g++) goff[g] = 0; }
  else { int pb = batch[t-1]; for (int g = pb+1; g <= b; g++) goff[g] = t; }
  if (t == N_-1) { for (int g = b+1; g <= G_; g++) goff[g] = N_; }
}

// ---------- fused lin1 + gate node precompute: 8 nodes/wave, LDS-broadcast ----------
__global__ void k_node8(const float* __restrict__ x, const float* __restrict__ lin1T,
                        const float* __restrict__ lin1b,
                        const float* __restrict__ w1aT, const float* __restrict__ w2T,
                        const float* __restrict__ attr,
                        float* __restrict__ x1o, float* __restrict__ g1,
                        float* __restrict__ g2, float* __restrict__ gr) {
  __shared__ float ts[4][8][64];
  int w = threadIdx.x >> 6, lane = threadIdx.x & 63;
  int base = (blockIdx.x*4 + w)*8;
  if (base >= N_) return;
  #pragma unroll
  for (int r = 0; r < 8; r++) {
    int row = min(base + r, N_-1);
    ts[w][r][lane] = x[(size_t)row*64 + lane];
  }
  float a[8];
  #pragma unroll
  for (int r = 0; r < 8; r++) a[r] = lin1b[lane];
  #pragma unroll 1
  for (int k4 = 0; k4 < 64; k4 += 4) {
    float4 x4[8];
    #pragma unroll
    for (int r = 0; r < 8; r++) x4[r] = *(const float4*)&ts[w][r][k4];
    #pragma unroll
    for (int kk = 0; kk < 4; kk++) {
      float wv = lin1T[(k4+kk)*64 + lane];
      #pragma unroll
      for (int r = 0; r < 8; r++) a[r] += f4get(x4[r], kk) * wv;
    }
  }
  #pragma unroll
  for (int r = 0; r < 8; r++) {
    a[r] = lrelu(a[r]);
    if (base + r < N_) x1o[(size_t)(base+r)*64 + lane] = a[r];
    ts[w][r][lane] = a[r];                 // restage x1 (same wave)
  }
  float b1[8], b2[8];
  #pragma unroll
  for (int r = 0; r < 8; r++) { b1[r] = 0.f; b2[r] = 0.f; }
  #pragma unroll 1
  for (int k4 = 0; k4 < 64; k4 += 4) {
    float4 a4[8];
    #pragma unroll
    for (int r = 0; r < 8; r++) a4[r] = *(const float4*)&ts[w][r][k4];
    #pragma unroll
    for (int kk = 0; kk < 4; kk++) {
      float w1 = w1aT[(k4+kk)*64 + lane];
      float w2v = w2T[(k4+kk)*64 + lane];
      #pragma unroll
      for (int r = 0; r < 8; r++) {
        float xk = f4get(a4[r], kk);
        b1[r] += xk * w1;
        b2[r] += xk * w2v;
      }
    }
  }
  #pragma unroll
  for (int r = 0; r < 8; r++) {
    if (base + r < N_) {
      g1[(size_t)(base+r)*64 + lane] = b1[r];
      g2[(size_t)(base+r)*64 + lane] = b2[r];
    }
  }
  float at = attr[lane];
  #pragma unroll
  for (int r = 0; r < 8; r++) {
    float t = wsum64(a[r] * at);
    if (lane == 0 && base + r < N_) gr[base+r] = t;
  }
}

// ---------- GATE edge logits: 16 edges per wave, 16 lanes per edge ----------
__global__ void k_edge1(const int* __restrict__ ei, const float* __restrict__ eattr,
                        const float* __restrict__ g1, const float* __restrict__ gr,
                        const float* __restrict__ W1E, const float* __restrict__ attl,
                        const int* __restrict__ ipos, float* __restrict__ ae) {
  int wid = (blockIdx.x*blockDim.x + threadIdx.x) >> 6;
  int lane = threadIdx.x & 63;
  int g = lane >> 4, j = lane & 15;
  if (wid >= E_/16) return;
  int e0 = wid*16;
  float wr[64];
  #pragma unroll
  for (int i = 0; i < 16; i++) {
    float4 v = ((const float4*)W1E)[i*16 + j];
    wr[i*4+0] = v.x; wr[i*4+1] = v.y; wr[i*4+2] = v.z; wr[i*4+3] = v.w;
  }
  float4 al = ((const float4*)attl)[j];
  float ea[4]; int srce[4], dste[4], ip[4];
  #pragma unroll
  for (int it = 0; it < 4; it++) {
    int e = e0 + it*4 + g;
    ea[it] = eattr[(size_t)(e0 + it*4)*16 + lane];
    srce[it] = ei[e];
    dste[it] = ei[E_ + e];
    ip[it] = ipos[e];
  }
  float grv[4];
  #pragma unroll
  for (int it = 0; it < 4; it++) grv[it] = gr[dste[it]];
  // software-pipelined g1 row gathers (2-deep; 4-deep spills at 64-VGPR cap)
  float4 gv = *(const float4*)(g1 + (size_t)srce[0]*64 + j*4);
  #pragma unroll
  for (int it = 0; it < 4; it++) {
    float4 gnext;
    if (it < 3) gnext = *(const float4*)(g1 + (size_t)srce[it+1]*64 + j*4);
    float a0 = gv.x, a1 = gv.y, a2 = gv.z, a3 = gv.w;
    #pragma unroll
    for (int d = 0; d < 16; d++) {
      float ead = __shfl(ea[it], g*16 + d);
      a0 += ead * wr[0*16 + d];
      a1 += ead * wr[1*16 + d];
      a2 += ead * wr[2*16 + d];
      a3 += ead * wr[3*16 + d];
    }
    float t = lrelu(a0)*al.x + lrelu(a1)*al.y + lrelu(a2)*al.z + lrelu(a3)*al.w;
    t += __shfl_xor(t, 1); t += __shfl_xor(t, 2);
    t += __shfl_xor(t, 4); t += __shfl_xor(t, 8);
    if (j == 0) ae[ip[it]] = lrelu(t + grv[it]);
    gv = gnext;
  }
}

// ---------- segmented softmax-attention reduce (wave per segment, no atomics/LDS) ----------
template<int MODE>
__global__ void k_seg(const float* __restrict__ aval, const float* __restrict__ asrc,
                      const float* __restrict__ adst, const int* __restrict__ srcS,
                      const int* __restrict__ off, const float* __restrict__ X,
                      float* __restrict__ out, int nseg) {
  int wid = (blockIdx.x*blockDim.x + threadIdx.x) >> 6;
  int lane = threadIdx.x & 63;
  if (wid >= nseg) return;
  int s0 = off[wid], s1 = off[wid+1];
  float adc = MODE ? adst[wid] : 0.f;
  float m = -1e30f, s = 0.f, acc = 0.f;
  for (int b = s0; b < s1; b += 64) {
    int p = b + lane;
    bool ok = p < s1;
    int sr = 0; float v = -1e30f;
    if (ok) {
      sr = srcS ? srcS[p] : p;
      if (MODE) v = lrelu(asrc[sr] + adc);
      else      v = aval[p];
    }
    float cm = v;
    #pragma unroll
    for (int o = 32; o > 0; o >>= 1) cm = fmaxf(cm, __shfl_xor(cm, o));
    float mnew = fmaxf(m, cm);
    float scale = __expf(m - mnew);
    s *= scale; acc *= scale; m = mnew;
    float ev = ok ? __expf(v - m) : 0.f;
    s += wsum64(ev);
    int cnt = min(64, s1 - b);
    int q = 0;
    for (; q + 4 <= cnt; q += 4) {
      int   i0 = __shfl(sr, q),   i1 = __shfl(sr, q+1),
            i2 = __shfl(sr, q+2), i3 = __shfl(sr, q+3);
      float w0 = __shfl(ev, q),   w1 = __shfl(ev, q+1),
            w2 = __shfl(ev, q+2), w3 = __shfl(ev, q+3);
      float v0 = X[(size_t)i0*64 + lane];
      float v1 = X[(size_t)i1*64 + lane];
      float v2 = X[(size_t)i2*64 + lane];
      float v3 = X[(size_t)i3*64 + lane];
      acc += w0*v0; acc += w1*v1; acc += w2*v2; acc += w3*v3;
    }
    for (; q < cnt; q++) {
      int i0 = __shfl(sr, q);
      float w0 = __shfl(ev, q);
      acc += w0 * X[(size_t)i0*64 + lane];
    }
  }
  out[(size_t)wid*64 + lane] = acc / (s + 1e-16f);
}

// ---------- mol-readout segmented softmax: block (4 waves) per graph, LDS merge ----------
__global__ void k_segg(const float* __restrict__ asrc, const float* __restrict__ adst,
                       const int* __restrict__ goff, const float* __restrict__ X,
                       float* __restrict__ out) {
  __shared__ float mS[4], sS[4], accS[4][64];
  int gph = blockIdx.x;
  int lane = threadIdx.x & 63, w = threadIdx.x >> 6;
  int s0 = goff[gph], s1 = goff[gph+1];
  float adc = adst[gph];
  int len = s1 - s0;
  int qlen = (len + 3) >> 2;
  int a0 = s0 + w*qlen, a1 = min(s1, a0 + qlen);
  float m = -1e30f, s = 0.f, acc = 0.f;
  for (int b = a0; b < a1; b += 64) {
    int p = b + lane;
    bool ok = p < a1;
    float v = ok ? lrelu(asrc[p] + adc) : -1e30f;
    float cm = v;
    #pragma unroll
    for (int o = 32; o > 0; o >>= 1) cm = fmaxf(cm, __shfl_xor(cm, o));
    float mnew = fmaxf(m, cm);
    float scale = __expf(m - mnew);
    s *= scale; acc *= scale; m = mnew;
    float ev = ok ? __expf(v - m) : 0.f;
    s += wsum64(ev);
    int cnt = min(64, a1 - b);
    int q = 0;
    for (; q + 4 <= cnt; q += 4) {
      float w0 = __shfl(ev, q),   w1 = __shfl(ev, q+1),
            w2 = __shfl(ev, q+2), w3 = __shfl(ev, q+3);
      float v0 = X[(size_t)(b+q  )*64 + lane];
      float v1 = X[(size_t)(b+q+1)*64 + lane];
      float v2 = X[(size_t)(b+q+2)*64 + lane];
      float v3 = X[(size_t)(b+q+3)*64 + lane];
      acc += w0*v0; acc += w1*v1; acc += w2*v2; acc += w3*v3;
    }
    for (; q < cnt; q++) acc += __shfl(ev, q) * X[(size_t)(b+q)*64 + lane];
  }
  if (lane == 0) { mS[w] = m; sS[w] = s; }
  accS[w][lane] = acc;
  __syncthreads();
  if (w == 0) {
    float m0 = fmaxf(fmaxf(mS[0], mS[1]), fmaxf(mS[2], mS[3]));
    float e0 = __expf(mS[0]-m0), e1 = __expf(mS[1]-m0),
          e2 = __expf(mS[2]-m0), e3 = __expf(mS[3]-m0);
    float st = sS[0]*e0 + sS[1]*e1 + sS[2]*e2 + sS[3]*e3;
    float at = accS[0][lane]*e0 + accS[1][lane]*e1 + accS[2][lane]*e2 + accS[3][lane]*e3;
    out[(size_t)gph*64 + lane] = at / (st + 1e-16f);
  }
}

// ---------- GRU (8 nodes/wave, LDS-broadcast, single pass, merged r/z accumulators) ----------
template<bool MV>
__global__ void k_gru8(const float* __restrict__ hpre, const float* __restrict__ bpre,
                       const float* __restrict__ hx,
                       const float* __restrict__ WihT, const float* __restrict__ WhhT,
                       const float* __restrict__ bih, const float* __restrict__ bhh,
                       float* __restrict__ outg, int n,
                       const float* __restrict__ WT, const float* __restrict__ v1,
                       const float* __restrict__ v2,
                       float* __restrict__ y, float* __restrict__ d1,
                       float* __restrict__ d2) {
  __shared__ float hs[4][8][64], xs[4][8][64];     // 16 KB
  int w = threadIdx.x >> 6, lane = threadIdx.x & 63;
  int base = (blockIdx.x*4 + w)*8;
  if (base >= n) return;
  #pragma unroll
  for (int r = 0; r < 8; r++) {
    int row = min(base + r, n-1);
    float hv = hpre[(size_t)row*64 + lane] + bpre[lane];
    hv = hv > 0.f ? hv : expm1f(hv);               // elu
    hs[w][r][lane] = hv;
    xs[w][r][lane] = hx[(size_t)row*64 + lane];
  }
  float a0[8], a1[8], ni[8], nh[8];
  #pragma unroll
  for (int r = 0; r < 8; r++) {
    a0[r] = bih[lane]    + bhh[lane];
    a1[r] = bih[64+lane] + bhh[64+lane];
    ni[r] = bih[128+lane];
    nh[r] = bhh[128+lane];
  }
  #pragma unroll 1
  for (int k2 = 0; k2 < 64; k2 += 2) {
    float2 h2[8], x2[8];
    #pragma unroll
    for (int r = 0; r < 8; r++) {
      h2[r] = *(const float2*)&hs[w][r][k2];       // uniform addr -> broadcast
      x2[r] = *(const float2*)&xs[w][r][k2];
    }
    #pragma unroll
    for (int kk = 0; kk < 2; kk++) {
      int k = k2 + kk;
      const float* wi = WihT + k*192;
      const float* wh = WhhT + k*192;
      float wi0 = wi[lane], wi1 = wi[64+lane], wi2 = wi[128+lane];
      float wh0 = wh[lane], wh1 = wh[64+lane], wh2 = wh[128+lane];
      #pragma unroll
      for (int r = 0; r < 8; r++) {
        float hk = kk ? h2[r].y : h2[r].x;
        float xk = kk ? x2[r].y : x2[r].x;
        a0[r] += hk*wi0; a0[r] += xk*wh0;
        a1[r] += hk*wi1; a1[r] += xk*wh1;
        ni[r] += hk*wi2; nh[r] += xk*wh2;
      }
    }
  }
  float o[8];
  #pragma unroll
  for (int r = 0; r < 8; r++) {
    float rr = 1.f/(1.f+__expf(-a0[r]));
    float zz = 1.f/(1.f+__expf(-a1[r]));
    float nn = tanhf(ni[r] + rr*nh[r]);
    float xv = xs[w][r][lane];
    float ov = (1.f - zz)*nn + zz*xv;
    o[r] = ov > 0.f ? ov : 0.f;                    // relu
    if (base + r < n) outg[(size_t)(base+r)*64 + lane] = o[r];
  }
  if (MV) {
    #pragma unroll
    for (int r = 0; r < 8; r++) hs[w][r][lane] = o[r];   // restage (same wave)
    float ay[8];
    #pragma unroll
    for (int r = 0; r < 8; r++) ay[r] = 0.f;
    #pragma unroll 1
    for (int k4 = 0; k4 < 64; k4 += 4) {
      float4 o4[8];
      #pragma unroll
      for (int r = 0; r < 8; r++) o4[r] = *(const float4*)&hs[w][r][k4];
      #pragma unroll
      for (int kk = 0; kk < 4; kk++) {
        float wv = WT[(k4+kk)*64 + lane];
        #pragma unroll
        for (int r = 0; r < 8; r++) ay[r] += f4get(o4[r], kk) * wv;
      }
    }
    #pragma unroll
    for (int r = 0; r < 8; r++)
      if (base + r < n) y[(size_t)(base+r)*64 + lane] = ay[r];
    float va = v1[lane];
    #pragma unroll
    for (int r = 0; r < 8; r++) {
      float t = wsum64(ay[r] * va);
      if (lane == 0 && base + r < n) d1[base+r] = t;
    }
    if (v2) {
      float vb = v2[lane];
      #pragma unroll
      for (int r = 0; r < 8; r++) {
        float t = wsum64(ay[r] * vb);
        if (lane == 0 && base + r < n) d2[base+r] = t;
      }
    }
  }
}

// ---------- small GRU for mol readout (4 rows/wave, unroll 2) ----------
__global__ void k_gru_sm(const float* __restrict__ hpre, const float* __restrict__ bpre,
                         const float* __restrict__ hx,
                         const float* __restrict__ WihT, const float* __restrict__ WhhT,
                         const float* __restrict__ bih, const float* __restrict__ bhh,
                         float* __restrict__ outg, int n) {
  int wid = (blockIdx.x*blockDim.x + threadIdx.x) >> 6;
  int lane = threadIdx.x & 63;
  int base = wid*4;
  if (base >= n) return;
  float h[4], xv[4];
  #pragma unroll
  for (int r = 0; r < 4; r++) {
    float hv = hpre[(size_t)(base+r)*64 + lane] + bpre[lane];
    h[r] = hv > 0.f ? hv : expm1f(hv);
    xv[r] = hx[(size_t)(base+r)*64 + lane];
  }
  float ai[4][3], ah[4][3];
  #pragma unroll
  for (int r = 0; r < 4; r++)
    #pragma unroll
    for (int g = 0; g < 3; g++) {
      ai[r][g] = bih[g*64 + lane];
      ah[r][g] = bhh[g*64 + lane];
    }
  #pragma unroll 2
  for (int k = 0; k < 64; k++) {
    const float* wi = WihT + k*192;
    const float* wh = WhhT + k*192;
    float wi0 = wi[lane], wi1 = wi[64+lane], wi2 = wi[128+lane];
    float wh0 = wh[lane], wh1 = wh[64+lane], wh2 = wh[128+lane];
    #pragma unroll
    for (int r = 0; r < 4; r++) {
      float hk = __shfl(h[r], k);
      float xk = __shfl(xv[r], k);
      ai[r][0] += hk*wi0; ai[r][1] += hk*wi1; ai[r][2] += hk*wi2;
      ah[r][0] += xk*wh0; ah[r][1] += xk*wh1; ah[r][2] += xk*wh2;
    }
  }
  #pragma unroll
  for (int r = 0; r < 4; r++) {
    float rr = 1.f/(1.f+__expf(-(ai[r][0]+ah[r][0])));
    float zz = 1.f/(1.f+__expf(-(ai[r][1]+ah[r][1])));
    float nn = tanhf(ai[r][2] + rr*ah[r][2]);
    float ov = (1.f - zz)*nn + zz*xv[r];
    outg[(size_t)(base+r)*64 + lane] = ov > 0.f ? ov : 0.f;
  }
}

// ---------- global_add_pool + relu: block (4 waves) per graph ----------
__global__ void k_pool4(const float* __restrict__ x3, const int* __restrict__ goff,
                        float* __restrict__ pool) {
  __shared__ float red[4][64];
  int gph = blockIdx.x;
  int lane = threadIdx.x & 63, w = threadIdx.x >> 6;
  int s0 = goff[gph], s1 = goff[gph+1];
  float acc = 0.f;
  for (int n = s0 + w; n < s1; n += 4) acc += x3[(size_t)n*64 + lane];
  red[w][lane] = acc;
  __syncthreads();
  if (w == 0) {
    float t = red[0][lane] + red[1][lane] + red[2][lane] + red[3][lane];
    pool[(size_t)gph*64 + lane] = fmaxf(t, 0.f);
  }
}

// ---------- per-graph dot with wv ----------
__global__ void k_dotg(const float* __restrict__ pool, const float* __restrict__ wv,
                       float* __restrict__ adg) {
  int wid = (blockIdx.x*blockDim.x + threadIdx.x) >> 6;
  int lane = threadIdx.x & 63;
  if (wid >= G_) return;
  float t = wsum64(pool[wid*64+lane] * wv[lane]);
  if (lane == 0) adg[wid] = t;
}

// ---------- final projection ----------
__global__ void k_final(const float* __restrict__ pool, const float* __restrict__ w2,
                        const float* __restrict__ b2, float* __restrict__ out) {
  int wid = (blockIdx.x*blockDim.x + threadIdx.x) >> 6;
  int lane = threadIdx.x & 63;
  if (wid >= G_) return;
  float t = wsum64(pool[wid*64+lane] * w2[lane]);
  if (lane == 0) out[wid] = t + b2[0];
}

// ---------- launcher ----------
extern "C" void kernel_launch(void* const* d_in, const int* in_sizes, int n_in,
                              void* d_out, int out_size, void* d_ws, size_t ws_size,
                              hipStream_t stream) {
  const float* x     = (const float*)d_in[0];
  const int*   ei    = (const int*)d_in[1];
  const float* eattr = (const float*)d_in[2];
  const int*   batch = (const int*)d_in[3];
  const float* lin1W = (const float*)d_in[4];
  const float* lin1b = (const float*)d_in[5];
  const float* gattl = (const float*)d_in[6];
  const float* gattr = (const float*)d_in[7];
  const float* gW1   = (const float*)d_in[8];
  const float* gW2   = (const float*)d_in[9];
  const float* gb    = (const float*)d_in[10];
  const float* g0ih  = (const float*)d_in[11];
  const float* g0hh  = (const float*)d_in[12];
  const float* g0bih = (const float*)d_in[13];
  const float* g0bhh = (const float*)d_in[14];
  const float* g1ih  = (const float*)d_in[15];
  const float* g1hh  = (const float*)d_in[16];
  const float* g1bih = (const float*)d_in[17];
  const float* g1bhh = (const float*)d_in[18];
  const float* mgih  = (const float*)d_in[19];
  const float* mghh  = (const float*)d_in[20];
  const float* mgbih = (const float*)d_in[21];
  const float* mgbhh = (const float*)d_in[22];
  const float* atomW = (const float*)d_in[23];
  const float* atomAs= (const float*)d_in[24];
  const float* atomAd= (const float*)d_in[25];
  const float* atomB = (const float*)d_in[26];
  const float* molW  = (const float*)d_in[27];
  const float* molAs = (const float*)d_in[28];
  const float* molAd = (const float*)d_in[29];
  const float* molB  = (const float*)d_in[30];
  const float* lin2W = (const float*)d_in[31];
  const float* lin2b = (const float*)d_in[32];
  float* out = (float*)d_out;
  float* w = (float*)d_ws;

  // ws allocation (floats, 64-aligned)
  size_t o = 0;
  auto alloc = [&](size_t nf){ size_t r = o; o += (nf + 63) & ~(size_t)63; return r; };
  float* tw   = w + alloc(TW_TOTAL);
  float* bufA = w + alloc((size_t)N_*64);   // x1 -> (seg atom out) -> x3
  float* bufB = w + alloc((size_t)N_*64);   // g1 -> (seg gate out) -> x2
  float* bufC = w + alloc((size_t)N_*64);   // g2 -> xs_atom -> xs_mol
  float* ae   = w + alloc(E_);              // sorted GATE logits
  int* srcS   = (int*)(w + alloc(E_));      // src sorted by dst
  int* ipos   = (int*)(w + alloc(E_));      // edge -> sorted position
  int* cnt    = (int*)(w + alloc(2*N_));    // cnt[N] + rnk[N] (contiguous for memset)
  int* rnk    = cnt + N_;
  int* off    = (int*)(w + alloc(N_+1));
  float* gr   = w + alloc(N_);
  float* as_  = w + alloc(N_);
  float* ad_  = w + alloc(N_);
  int* goff   = (int*)(w + alloc(G_+1));
  float* pool = w + alloc((size_t)G_*64);
  float* hg   = w + alloc((size_t)G_*64);
  float* adg  = w + alloc(G_);
  (void)rnk;

  const int TB = 256;
  const int NB_nw  = (N_+3)/4;       // wave-per-node blocks (12500)
  const int NB_n32 = (N_+31)/32;     // 4-waves x 8-nodes blocks (1563)
  const int NB_g16 = G_/16;          // 64
  const int NB_e   = (E_+TB-1)/TB;   // thread-per-edge (3125)
  const int NB_n   = (N_+TB-1)/TB;   // thread-per-node (196)
  const int NB_e16 = E_/16/4;        // 16-edges-per-wave blocks (12500)
  const int NB_gw  = G_/4;           // wave-per-graph (256)

  hipMemsetAsync(cnt, 0, (size_t)2*N_*sizeof(int), stream);
  k_prep<<<(TW_TOTAL+TB-1)/TB, TB, 0, stream>>>(lin1W, gW1, gW2, atomW, molW, molAd,
      g0ih, g0hh, g1ih, g1hh, mgih, mghh, tw);
  // counting sort of edges by dst
  k_hist<<<NB_e, TB, 0, stream>>>(ei, cnt);
  k_scan<<<1, 1024, 0, stream>>>(cnt, off);
  k_rank<<<NB_e, TB, 0, stream>>>(ei, off, rnk, srcS, ipos);
  k_goff<<<NB_n, TB, 0, stream>>>(batch, goff);

  // fused lin1 + GATE node precompute (8 nodes/wave)
  k_node8<<<NB_n32, TB, 0, stream>>>(x, tw+OFF_LIN1T, lin1b, tw+OFF_W1AT, tw+OFF_W2T,
                                     gattr, bufA, bufB, bufC, gr);
  // GATEConv edge pass + segmented softmax reduce
  k_edge1<<<NB_e16, TB, 0, stream>>>(ei, eattr, bufB, gr, tw+OFF_W1E, gattl, ipos, ae);
  k_seg<0><<<NB_nw, TB, 0, stream>>>(ae, nullptr, nullptr, srcS, off, bufC, bufB, N_);
  // gru0 (8 nodes/wave) fused with atom-GAT matvec + dots: x2 in bufB, xs_atom in bufC
  k_gru8<true><<<NB_n32, TB, 0, stream>>>(bufB, gb, bufA, tw+OFF_G0IH, tw+OFF_G0HH,
      g0bih, g0bhh, bufB, N_, tw+OFF_ATOMT, atomAs, atomAd, bufC, as_, ad_);
  // atom GAT reduce
  k_seg<1><<<NB_nw, TB, 0, stream>>>(nullptr, as_, ad_, srcS, off, bufC, bufA, N_);
  // gru1 fused with mol matvec + as dot: x3 in bufA, xs_mol in bufC
  k_gru8<true><<<NB_n32, TB, 0, stream>>>(bufA, atomB, bufB, tw+OFF_G1IH, tw+OFF_G1HH,
      g1bih, g1bhh, bufA, N_, tw+OFF_MOLT, molAs, nullptr, bufC, as_, nullptr);
  // readout: block-per-graph pool
  k_pool4<<<G_, TB, 0, stream>>>(bufA, goff, pool);
  for (int t = 0; t < 2; t++) {
    k_dotg<<<NB_gw, TB, 0, stream>>>(pool, tw+OFF_WV, adg);
    k_segg<<<G_, TB, 0, stream>>>(as_, adg, goff, bufC, hg);
    k_gru_sm<<<NB_g16, TB, 0, stream>>>(hg, molB, pool, tw+OFF_MGIH, tw+OFF_MGHH,
        mgbih, mgbhh, pool, G_);
  }
  k_final<<<NB_gw, TB, 0, stream>>>(pool, lin2W, lin2b, out);
}